// Round 13
// baseline (189.171 us; speedup 1.0000x reference)
//
#include <hip/hip_runtime.h>
#include <hip/hip_bf16.h>

// Shapes: bz=32, rv_num=10, rv_len=128, in_feat=300, out_feat=128
// R13: two-kernel structure; fc with TM=64 (grid 1280, ~4 blocks/CU),
// double-buffered LDS A staging (1 barrier/chunk), W direct-from-L2
// fragments, swapped-operand MFMA (D[h][tok]), bf16 packed stores.

#define K_FEAT 300
#define H 128
#define NTOK 40960
#define NREV 320
#define TOK_PER_SAMPLE 1280
#define BLKS_PER_SAMPLE 20          // 1280/64 fc blocks per sample
#define TM 64
#define LDA 40                      // LDS row stride in bf16 (32 k + 8 pad)
#define NCHUNK 10
#define WFRAG_ELEMS (NCHUNK * 8 * 2 * 64 * 8)   // 81920 bf16 = 160 KB

typedef __attribute__((ext_vector_type(8))) short bf16x8;
typedef __attribute__((ext_vector_type(4))) float f32x4;
typedef unsigned short u16;
typedef unsigned int u32;

static __device__ __forceinline__ u16 f2bf(float x) {
    u32 u = __float_as_uint(x);
    return (u16)((u + 0x7fffu + ((u >> 16) & 1u)) >> 16);
}
static __device__ __forceinline__ float bf2f(u16 s) {
    return __uint_as_float(((u32)s) << 16);
}

// ---------------- Kernel 0: pack W into per-(chunk,n-tile,part,lane) bf16 fragments -------
// Wfrag[c][n][part][lane][8]; part 0=hi, 1=lo. h = n*16 + (lane&15);
// k = c*32 + (lane>>4)*8 + j; zero-pad k >= 300. (R12-proven layout.)
__global__ void wsplit_kernel(const float* __restrict__ W, u16* __restrict__ Wfrag)
{
    int i = blockIdx.x * 256 + threadIdx.x;
    if (i >= WFRAG_ELEMS) return;
    int j    = i & 7;
    int lane = (i >> 3) & 63;
    int part = (i >> 9) & 1;
    int n    = (i >> 10) & 7;
    int c    = i >> 13;
    int h = n * 16 + (lane & 15);
    int k = c * 32 + (lane >> 4) * 8 + j;
    float w = (k < K_FEAT) ? W[(size_t)k * H + h] : 0.f;
    u16 hi = f2bf(w);
    Wfrag[i] = part ? f2bf(w - bf2f(hi)) : hi;
}

// ---------------- Kernel 1: FC + ReLU, TM=64, dbuf LDS, 3-term split-bf16 MFMA ------------
// grid.x = 1280 (640/side); block = 256 (4 waves). Wave = 16 tokens x 128 feats.
__global__ __launch_bounds__(256, 4) void fc_mfma_kernel(
    const float* __restrict__ seq_a, const float* __restrict__ seq_b,
    const u16* __restrict__ Wfrag, const float* __restrict__ bias,
    u16* __restrict__ ta, u16* __restrict__ tb,
    float* __restrict__ psum_a, float* __restrict__ psum_b)
{
    __shared__ u16 Ah_s[2][TM * LDA];   // 2 x 5120 B
    __shared__ u16 Al_s[2][TM * LDA];   // 2 x 5120 B
    __shared__ float psum_s[4][H];
    __shared__ float bias_s[H];

    int blk = blockIdx.x;
    const float* seq; u16* outp; float* psum;
    if (blk < 640) { seq = seq_a; outp = ta; psum = psum_a; }
    else           { seq = seq_b; outp = tb; psum = psum_b; blk -= 640; }

    const int tid = threadIdx.x;
    const int tok0 = blk * TM;
    const int wave = tid >> 6;
    const int lane = tid & 63;
    const int nn = lane & 15;
    const int quad = lane >> 4;

    if (tid < H) bias_s[tid] = bias[tid];

    // staging coords: element i = tid + it*256 (it<2): tok = i>>3, j = i&7
    const int st_tok = tid >> 3;        // 0..31, +32 for it=1
    const int st_j = tid & 7;

    f32x4 acc[8];                       // [n-tile]
#pragma unroll
    for (int n = 0; n < 8; ++n) acc[n] = (f32x4){0.f, 0.f, 0.f, 0.f};

    float4 pf[2];
    // prologue: chunk 0 loads (k <= 31 < 300, unconditional), convert, write buf 0
#pragma unroll
    for (int it = 0; it < 2; ++it)
        pf[it] = *(const float4*)&seq[(size_t)(tok0 + st_tok + it * 32) * K_FEAT + 4 * st_j];
#pragma unroll
    for (int it = 0; it < 2; ++it) {
        int t = st_tok + it * 32;
        float4 v = pf[it];
        u16 h0 = f2bf(v.x), h1 = f2bf(v.y), h2 = f2bf(v.z), h3 = f2bf(v.w);
        uint2 hp, lp;
        hp.x = (u32)h0 | ((u32)h1 << 16);
        hp.y = (u32)h2 | ((u32)h3 << 16);
        lp.x = (u32)f2bf(v.x - bf2f(h0)) | ((u32)f2bf(v.y - bf2f(h1)) << 16);
        lp.y = (u32)f2bf(v.z - bf2f(h2)) | ((u32)f2bf(v.w - bf2f(h3)) << 16);
        *(uint2*)&Ah_s[0][t * LDA + 4 * st_j] = hp;
        *(uint2*)&Al_s[0][t * LDA + 4 * st_j] = lp;
    }

    for (int c = 0; c < NCHUNK; ++c) {
        __syncthreads();    // buf[c&1] fully staged; prior readers of buf[(c+1)&1] done
        // prefetch chunk c+1 A loads (hidden behind MFMA below)
        if (c < NCHUNK - 1) {
            int kk = (c + 1) * 32 + 4 * st_j;
            float4 z = make_float4(0.f, 0.f, 0.f, 0.f);
#pragma unroll
            for (int it = 0; it < 2; ++it)
                pf[it] = (kk + 4 <= K_FEAT)
                    ? *(const float4*)&seq[(size_t)(tok0 + st_tok + it * 32) * K_FEAT + kk] : z;
        }
        // A fragments for this wave's 16 tokens
        bf16x8 ah = *(const bf16x8*)&Ah_s[c & 1][(wave * 16 + nn) * LDA + quad * 8];
        bf16x8 al = *(const bf16x8*)&Al_s[c & 1][(wave * 16 + nn) * LDA + quad * 8];
        // W fragments: coalesced L2 loads, software double-buffered over n
        const u16* wbase = Wfrag + (size_t)c * (8 * 2 * 512);
        bf16x8 wh = *(const bf16x8*)&wbase[0 * 1024 + 0 + lane * 8];
        bf16x8 wl = *(const bf16x8*)&wbase[0 * 1024 + 512 + lane * 8];
#pragma unroll
        for (int n = 0; n < 8; ++n) {
            bf16x8 whc = wh, wlc = wl;
            if (n < 7) {
                wh = *(const bf16x8*)&wbase[(n + 1) * 1024 + 0 + lane * 8];
                wl = *(const bf16x8*)&wbase[(n + 1) * 1024 + 512 + lane * 8];
            }
            // swapped operands: D[h][tok]
            acc[n] = __builtin_amdgcn_mfma_f32_16x16x32_bf16(whc, ah, acc[n], 0, 0, 0);
            acc[n] = __builtin_amdgcn_mfma_f32_16x16x32_bf16(wlc, ah, acc[n], 0, 0, 0);
            acc[n] = __builtin_amdgcn_mfma_f32_16x16x32_bf16(whc, al, acc[n], 0, 0, 0);
        }
        // stage chunk c+1 into the other buffer (no barrier until next iteration)
        if (c < NCHUNK - 1) {
#pragma unroll
            for (int it = 0; it < 2; ++it) {
                int t = st_tok + it * 32;
                float4 v = pf[it];
                u16 h0 = f2bf(v.x), h1 = f2bf(v.y), h2 = f2bf(v.z), h3 = f2bf(v.w);
                uint2 hp, lp;
                hp.x = (u32)h0 | ((u32)h1 << 16);
                hp.y = (u32)h2 | ((u32)h3 << 16);
                lp.x = (u32)f2bf(v.x - bf2f(h0)) | ((u32)f2bf(v.y - bf2f(h1)) << 16);
                lp.y = (u32)f2bf(v.z - bf2f(h2)) | ((u32)f2bf(v.w - bf2f(h3)) << 16);
                *(uint2*)&Ah_s[(c + 1) & 1][t * LDA + 4 * st_j] = hp;
                *(uint2*)&Al_s[(c + 1) & 1][t * LDA + 4 * st_j] = lp;
            }
        }
    }

    // Epilogue: bias + ReLU, packed bf16 stores.
    // Lane holds h = n*16 + quad*4 + reg, tok = tok0 + wave*16 + nn.
    int tok = tok0 + wave * 16 + nn;
#pragma unroll
    for (int n = 0; n < 8; ++n) {
        float4 bb = *(const float4*)&bias_s[n * 16 + quad * 4];
        float v0 = fmaxf(acc[n][0] + bb.x, 0.f);
        float v1 = fmaxf(acc[n][1] + bb.y, 0.f);
        float v2 = fmaxf(acc[n][2] + bb.z, 0.f);
        float v3 = fmaxf(acc[n][3] + bb.w, 0.f);
        acc[n][0] = v0; acc[n][1] = v1; acc[n][2] = v2; acc[n][3] = v3;
        uint2 p;
        p.x = (u32)f2bf(v0) | ((u32)f2bf(v1) << 16);
        p.y = (u32)f2bf(v2) | ((u32)f2bf(v3) << 16);
        *(uint2*)&outp[(size_t)tok * H + n * 16 + quad * 4] = p;
    }

    // psum: per-feature sums over the block's 64 tokens
#pragma unroll
    for (int n = 0; n < 8; ++n) {
        float s0 = acc[n][0], s1 = acc[n][1], s2 = acc[n][2], s3 = acc[n][3];
        s0 += __shfl_xor(s0, 1); s0 += __shfl_xor(s0, 2); s0 += __shfl_xor(s0, 4); s0 += __shfl_xor(s0, 8);
        s1 += __shfl_xor(s1, 1); s1 += __shfl_xor(s1, 2); s1 += __shfl_xor(s1, 4); s1 += __shfl_xor(s1, 8);
        s2 += __shfl_xor(s2, 1); s2 += __shfl_xor(s2, 2); s2 += __shfl_xor(s2, 4); s2 += __shfl_xor(s2, 8);
        s3 += __shfl_xor(s3, 1); s3 += __shfl_xor(s3, 2); s3 += __shfl_xor(s3, 4); s3 += __shfl_xor(s3, 8);
        if (nn == 0) {
            psum_s[wave][n * 16 + quad * 4 + 0] = s0;
            psum_s[wave][n * 16 + quad * 4 + 1] = s1;
            psum_s[wave][n * 16 + quad * 4 + 2] = s2;
            psum_s[wave][n * 16 + quad * 4 + 3] = s3;
        }
    }
    __syncthreads();
    if (tid < H)
        psum[(size_t)blk * H + tid] = psum_s[0][tid] + psum_s[1][tid]
                                    + psum_s[2][tid] + psum_s[3][tid];
}

// ---------------- Kernel 2: scores -> masked softmax -> weighted sum (R12-proven, bf16) ---
__global__ __launch_bounds__(256) void attn_kernel(
    const u16* __restrict__ ta, const u16* __restrict__ tb,
    const int* __restrict__ mask_a, const int* __restrict__ mask_b,
    const float* __restrict__ psum_a, const float* __restrict__ psum_b,
    float* __restrict__ out)
{
    int n = blockIdx.x;
    int side = 0;
    if (n >= NREV) { side = 1; n -= NREV; }

    const u16* t = side ? tb : ta;
    const int* mask = side ? mask_b : mask_a;
    const float* psum_o = side ? psum_a : psum_b;   // partial sums of the OTHER side
    float* out_vec = out + (side ? NREV * H : 0);
    float* out_w = out + 2 * NREV * H + (side ? NREV * H : 0);

    int sample = n / 10;
    int tid = threadIdx.x;

    __shared__ float score_part[128 * 17];
    __shared__ float mean_s[128];
    __shared__ float w_s[128];
    __shared__ float red[4];
    __shared__ float part_out[16 * 128];

    if (tid < 128) {
        float s = 0.f;
        const float* pb = psum_o + (size_t)sample * BLKS_PER_SAMPLE * H + tid;
#pragma unroll
        for (int i = 0; i < BLKS_PER_SAMPLE; ++i) s += pb[(size_t)i * H];
        mean_s[tid] = s * (1.0f / (float)TOK_PER_SAMPLE);
    }
    __syncthreads();

    const u16* rowbase = t + (size_t)n * 128 * H;

    // Phase 1: streaming score partials; uint4 = 8 bf16 per load, coalesced.
#pragma unroll
    for (int i = 0; i < 8; ++i) {
        int q = tid + 256 * i;
        int r = q >> 4;
        int c8 = q & 15;
        uint4 v = *(const uint4*)&rowbase[r * H + c8 * 8];
        const float* m = &mean_s[c8 * 8];
        float p = 0.f;
        p += bf2f((u16)(v.x & 0xffff)) * m[0];
        p += bf2f((u16)(v.x >> 16)) * m[1];
        p += bf2f((u16)(v.y & 0xffff)) * m[2];
        p += bf2f((u16)(v.y >> 16)) * m[3];
        p += bf2f((u16)(v.z & 0xffff)) * m[4];
        p += bf2f((u16)(v.z >> 16)) * m[5];
        p += bf2f((u16)(v.w & 0xffff)) * m[6];
        p += bf2f((u16)(v.w >> 16)) * m[7];
        score_part[r * 17 + c8] = p;
    }
    __syncthreads();

    // Phase 2: row sums -> masked softmax
    float logit = -1e9f;
    if (tid < 128) {
        float s = 0.f;
#pragma unroll
        for (int j = 0; j < 16; ++j) s += score_part[tid * 17 + j];
        int mv = mask[n * 128 + tid];
        logit = (mv > 0) ? s : -1e9f;
    }

    float mx = logit;
    for (int off = 32; off > 0; off >>= 1) mx = fmaxf(mx, __shfl_xor(mx, off));
    if ((tid & 63) == 0) red[tid >> 6] = mx;
    __syncthreads();
    mx = fmaxf(fmaxf(red[0], red[1]), fmaxf(red[2], red[3]));
    __syncthreads();

    float e = __expf(logit - mx);
    float ssum = e;
    for (int off = 32; off > 0; off >>= 1) ssum += __shfl_xor(ssum, off);
    if ((tid & 63) == 0) red[tid >> 6] = ssum;
    __syncthreads();
    ssum = red[0] + red[1] + red[2] + red[3];

    float w = e / ssum;
    if (tid < 128) {
        w_s[tid] = w;
        out_w[n * 128 + tid] = w;
    }
    __syncthreads();

    // Phase 3: out[d] = sum_l w_l * row_l[d] (rows L2-hot, bf16)
    int c8 = tid & 15;
    int lp = tid >> 4;
    float o[8] = {0.f, 0.f, 0.f, 0.f, 0.f, 0.f, 0.f, 0.f};
#pragma unroll
    for (int k = 0; k < 8; ++k) {
        int l = k * 16 + lp;
        float wl = w_s[l];
        uint4 v = *(const uint4*)&rowbase[l * H + c8 * 8];
        o[0] = fmaf(wl, bf2f((u16)(v.x & 0xffff)), o[0]);
        o[1] = fmaf(wl, bf2f((u16)(v.x >> 16)), o[1]);
        o[2] = fmaf(wl, bf2f((u16)(v.y & 0xffff)), o[2]);
        o[3] = fmaf(wl, bf2f((u16)(v.y >> 16)), o[3]);
        o[4] = fmaf(wl, bf2f((u16)(v.z & 0xffff)), o[4]);
        o[5] = fmaf(wl, bf2f((u16)(v.z >> 16)), o[5]);
        o[6] = fmaf(wl, bf2f((u16)(v.w & 0xffff)), o[6]);
        o[7] = fmaf(wl, bf2f((u16)(v.w >> 16)), o[7]);
    }
    *(float4*)&part_out[lp * 128 + c8 * 8] = make_float4(o[0], o[1], o[2], o[3]);
    *(float4*)&part_out[lp * 128 + c8 * 8 + 4] = make_float4(o[4], o[5], o[6], o[7]);
    __syncthreads();
    if (tid < 128) {
        float s = 0.f;
#pragma unroll
        for (int p = 0; p < 16; ++p) s += part_out[p * 128 + tid];
        out_vec[n * 128 + tid] = s;
    }
}

// ---------------- Launch ----------------
extern "C" void kernel_launch(void* const* d_in, const int* in_sizes, int n_in,
                              void* d_out, int out_size, void* d_ws, size_t ws_size,
                              hipStream_t stream)
{
    const float* seq_a = (const float*)d_in[0];
    const float* seq_b = (const float*)d_in[1];
    const int* mask_a = (const int*)d_in[2];
    const int* mask_b = (const int*)d_in[3];
    const float* W = (const float*)d_in[4];
    const float* bias = (const float*)d_in[5];
    float* out = (float*)d_out;

    u16* ta = (u16*)d_ws;                             // 40960*128 bf16
    u16* tb = ta + (size_t)NTOK * H;                  // 40960*128 bf16
    float* psum_a = (float*)(tb + (size_t)NTOK * H);  // 1280*128 f32 (20 blocks/sample * 32 * 2)
    float* psum_b = psum_a + 640 * H;                 // 640 fc blocks per side
    u16* Wfrag = (u16*)(psum_b + 640 * H);            // 81920 bf16

    wsplit_kernel<<<(WFRAG_ELEMS + 255) / 256, 256, 0, stream>>>(W, Wfrag);
    fc_mfma_kernel<<<1280, 256, 0, stream>>>(seq_a, seq_b, Wfrag, bias, ta, tb, psum_a, psum_b);
    attn_kernel<<<640, 256, 0, stream>>>(ta, tb, mask_a, mask_b, psum_a, psum_b, out);
}